// Round 1
// baseline (9947.993 us; speedup 1.0000x reference)
//
#include <hip/hip_runtime.h>
#include <math.h>

// Problem constants (match reference)
#define NB   32
#define NA   24564
#define NTOT (NB * NA)          // 786048 = 128 * 6141 exactly
#define NCH  85                 // 4 box deltas + 81 logits
#define TOPK 200
#define IOU_THR_F     0.5f
#define SCORE_FLOOR_F 0.01f

#define DEC_T 128               // decode block size (exact divisor of NTOT)
#define NMS_T 512               // nms block size
#define SLOTS ((NA + NMS_T - 1) / NMS_T)   // 48 anchors per thread

// ---------------------------------------------------------------------------
// Kernel 1: decode boxes + softmax score/cls per anchor.
// LDS-staged coalesced input; per-thread arithmetic BIT-IDENTICAL to the
// R1-passing version (strict __f*_rn, exp in double). DO NOT alter numerics.
// ---------------------------------------------------------------------------
__global__ __launch_bounds__(DEC_T) void decode_kernel(
    const float* __restrict__ x, const float* __restrict__ anchor,
    float4* __restrict__ boxes, float* __restrict__ scores,
    float* __restrict__ clsf)
{
    __shared__ float tile[DEC_T * NCH];            // 43,520 B -> 3 blocks/CU

    const int base = blockIdx.x * DEC_T;
    const float4* src = (const float4*)(x + (size_t)base * NCH);
    float4* dst = (float4*)tile;
    for (int k = threadIdx.x; k < DEC_T * NCH / 4; k += DEC_T) dst[k] = src[k];
    __syncthreads();

    const int g = base + threadIdx.x;
    const int i = g % NA;
    const float* row = tile + threadIdx.x * NCH;

    float ax = anchor[i * 4 + 0];
    float ay = anchor[i * 4 + 1];
    float aw = anchor[i * 4 + 2];
    float ah = anchor[i * 4 + 3];

    float d0 = row[0], d1 = row[1], d2 = row[2], d3 = row[3];
    float cx = __fadd_rn(__fdiv_rn(__fmul_rn(d0, aw), 10.0f), ax);
    float cy = __fadd_rn(__fdiv_rn(__fmul_rn(d1, ah), 10.0f), ay);
    float w = __fmul_rn((float)exp((double)__fdiv_rn(d2, 5.0f)), aw);
    float h = __fmul_rn((float)exp((double)__fdiv_rn(d3, 5.0f)), ah);
    float hw = __fmul_rn(w, 0.5f);
    float hh = __fmul_rn(h, 0.5f);
    boxes[g] = make_float4(__fsub_rn(cx, hw), __fsub_rn(cy, hh),
                           __fadd_rn(cx, hw), __fadd_rn(cy, hh));

    const float* z = row + 4;
    float m = z[0];
    #pragma unroll 9
    for (int k = 1; k < 81; k++) m = fmaxf(m, z[k]);

    double S = 0.0;
    double be = 0.0;
    float  bz = -INFINITY;
    int    bj = 0;
    for (int k = 0; k < 81; k++) {
        float zk = z[k];
        double e = exp((double)__fsub_rn(zk, m));
        S += e;
        if (k >= 1 && zk > bz) { bz = zk; be = e; bj = k - 1; }
    }
    scores[g] = (float)(be / S);
    clsf[g]   = (float)bj;
}

// ---------------------------------------------------------------------------
// IoU suppression predicate — EXACT op sequence of the reference:
//   area2 from candidate, clip extents to [0,1], denom = (a1+a2)-common,
//   correctly-rounded division, suppress on !(iou < 0.5) (NaN suppresses).
// DO NOT replace the division with an algebraic compare (1-ulp flips).
// ---------------------------------------------------------------------------
__device__ __forceinline__ bool suppressed_by(const float4 v, const float4 w,
                                              const float area_w)
{
    float area2 = __fmul_rn(__fsub_rn(v.z, v.x), __fsub_rn(v.w, v.y));
    float xl = fmaxf(w.x, v.x);
    float xr = fminf(w.z, v.z);
    float yt = fmaxf(w.y, v.y);
    float yb = fminf(w.w, v.w);
    float cw  = fminf(fmaxf(__fsub_rn(xr, xl), 0.0f), 1.0f);
    float chh = fminf(fmaxf(__fsub_rn(yb, yt), 0.0f), 1.0f);
    float common = __fmul_rn(cw, chh);
    float denom  = __fsub_rn(__fadd_rn(area_w, area2), common);
    float iou    = __fdiv_rn(common, denom);
    return !(iou < IOU_THR_F);
}

// ---------------------------------------------------------------------------
// Kernel 2: per-batch greedy NMS with LAZY suppression.
// One 512-thread block per batch. Boxes in registers (48/thread), aliveness
// as a u64 register mask, scores in LDS.
//
// Invariant: each thread maintains a "top" candidate = its max-score alive
// slot, verified unsuppressed vs ALL winners so far. Common path per
// iteration: ONE IoU (top vs newest winner) instead of 48. Slots are only
// fully verified (vs the LDS winner list s_wbox[0..t-1], early-exit) when
// promoted to top. Since winner = max over verified tops and verified tops
// dominate all truly-valid slots, the selected sequence is identical to the
// eager algorithm (== reference).
//
// Winner's box is published through LDS by the winning thread (it owns it in
// registers) — no per-iteration global broadcast load on the critical path.
// s_best is a pre-zeroed [TOPK] array: no reset, no double-buffer.
//
// __launch_bounds__(512, 1) is LOAD-BEARING: without it the compiler caps
// at 128 VGPRs and spills the box array to scratch (R3: 11.2 GB FETCH).
// CRITICAL (R2 bug): winner is killed EXPLICITLY — ref IoU clips
// intersection extents to [0,1] but not areas, so self-IoU can be < 0.5.
// ---------------------------------------------------------------------------
__global__ __launch_bounds__(NMS_T, 1) void nms_kernel(
    const float4* __restrict__ boxes, const float* __restrict__ scores,
    const float* __restrict__ clsf, float* __restrict__ out)
{
    __shared__ float s_score[NA];                  // 98,256 B
    __shared__ float4 s_wbox[TOPK];                //  3,200 B winner boxes
    __shared__ unsigned long long s_best[TOPK];    //  1,600 B argmax slots

    const int b   = blockIdx.x;
    const int tid = threadIdx.x;
    const float*  sc = scores + (size_t)b * NA;
    const float4* bx = boxes  + (size_t)b * NA;
    const float*  cf = clsf   + (size_t)b * NA;
    float* ob = out + (size_t)b * TOPK * 6;

    float4 box[SLOTS];
    unsigned long long alive = 0ULL;
    #pragma unroll
    for (int s = 0; s < SLOTS; s++) {
        int j = tid + s * NMS_T;
        box[s] = make_float4(0.0f, 0.0f, 0.0f, 0.0f);
        if (j < NA) { box[s] = bx[j]; alive |= (1ULL << s); }
    }
    for (int j = tid; j < NA; j += NMS_T) s_score[j] = sc[j];
    for (int k = tid; k < TOPK; k += NMS_T) s_best[k] = 0ULL;
    __syncthreads();

    // per-thread top-candidate state
    bool   tvalid = false;
    float  ts = 0.0f;
    int    tj = 0, tslot = 0;
    float4 tb = make_float4(0.0f, 0.0f, 0.0f, 0.0f);
    float4 ch = make_float4(0.0f, 0.0f, 0.0f, 0.0f);   // newest winner (t>0)
    float  area_ch = 0.0f;

    int t = 0;
    for (; t < TOPK; t++) {
        // ---- (A) maintain top: 1 IoU vs newest winner on the common path
        if (tvalid) {
            if (!((alive >> tslot) & 1ULL)) {
                tvalid = false;                         // was last winner
            } else if (t > 0 && suppressed_by(tb, ch, area_ch)) {
                alive &= ~(1ULL << tslot);
                tvalid = false;
            }
        }
        if (!tvalid) {
            // REPAIR (divergent, no barriers): promote best alive slot,
            // verifying vs full winner list with early exit.
            while (alive) {
                float bs = 0.0f; int bslot = -1;
                #pragma unroll
                for (int s = 0; s < SLOTS; s++) {
                    if (alive & (1ULL << s)) {
                        float v = s_score[tid + s * NMS_T];
                        // strict > + ascending s keeps smallest j on ties
                        if (v > bs) { bs = v; bslot = s; }
                    }
                }
                if (bslot < 0) break;                   // safety (scores > 0)
                float4 cb = make_float4(0.0f, 0.0f, 0.0f, 0.0f);
                #pragma unroll                          // static-index select
                for (int s = 0; s < SLOTS; s++) if (s == bslot) cb = box[s];
                bool killed = false;
                for (int k = 0; k < t; k++) {
                    float4 w = s_wbox[k];
                    float aw_ = __fmul_rn(__fsub_rn(w.z, w.x),
                                          __fsub_rn(w.w, w.y));
                    if (suppressed_by(cb, w, aw_)) { killed = true; break; }
                }
                if (killed) { alive &= ~(1ULL << bslot); continue; }
                ts = bs; tslot = bslot; tj = tid + bslot * NMS_T; tb = cb;
                tvalid = true;
                break;
            }
        }

        // ---- (B) block-wide argmax: pack (score, NA-j), shfl-reduce, atomic
        unsigned long long bestk = 0ULL;
        if (tvalid)
            bestk = ((unsigned long long)__float_as_uint(ts) << 32) |
                    (unsigned int)(NA - tj);
        #pragma unroll
        for (int off = 32; off > 0; off >>= 1) {
            unsigned long long o = __shfl_down(bestk, off, 64);
            if (o > bestk) bestk = o;
        }
        if ((tid & 63) == 0) atomicMax(&s_best[t], bestk);
        __syncthreads();

        // ---- (C) winner publish
        unsigned long long wk = s_best[t];
        float bscore = __uint_as_float((unsigned int)(wk >> 32));
        if (!(bscore >= SCORE_FLOOR_F)) break;          // exhausted -> zeros
        int widx = NA - (int)(wk & 0xFFFFFFFFu);

        if (tvalid && widx == tj) {                     // winner == my top
            alive &= ~(1ULL << tslot);                  // EXPLICIT self-kill
            tvalid = false;
            s_wbox[t] = tb;                             // publish via LDS
            ob[t * 6 + 0] = cf[widx];
            ob[t * 6 + 1] = bscore;
            ob[t * 6 + 2] = tb.x;
            ob[t * 6 + 3] = tb.y;
            ob[t * 6 + 4] = tb.z;
            ob[t * 6 + 5] = tb.w;
        }
        __syncthreads();

        ch = s_wbox[t];                                 // LDS broadcast read
        area_ch = __fmul_rn(__fsub_rn(ch.z, ch.x), __fsub_rn(ch.w, ch.y));
    }

    for (int k = t * 6 + tid; k < TOPK * 6; k += NMS_T) ob[k] = 0.0f;
}

// ---------------------------------------------------------------------------
extern "C" void kernel_launch(void* const* d_in, const int* in_sizes, int n_in,
                              void* d_out, int out_size, void* d_ws, size_t ws_size,
                              hipStream_t stream) {
    const float* x      = (const float*)d_in[0];   // (32, 24564, 85)
    const float* anchor = (const float*)d_in[1];   // (24564, 4)
    float* out = (float*)d_out;                    // (32, 200, 6)

    char* ws = (char*)d_ws;
    const size_t boxes_bytes  = (size_t)NTOT * 16;
    const size_t scores_off   = (boxes_bytes + 255) & ~255ULL;
    const size_t scores_bytes = (size_t)NTOT * 4;
    const size_t cls_off      = (scores_off + scores_bytes + 255) & ~255ULL;

    float4* boxes  = (float4*)ws;
    float*  scores = (float*)(ws + scores_off);
    float*  clsf   = (float*)(ws + cls_off);

    decode_kernel<<<NTOT / DEC_T, DEC_T, 0, stream>>>(x, anchor, boxes, scores, clsf);
    nms_kernel<<<NB, NMS_T, 0, stream>>>(boxes, scores, clsf, out);
}

// Round 2
// 2026.414 us; speedup vs baseline: 4.9092x; 4.9092x over previous
//
#include <hip/hip_runtime.h>
#include <math.h>

// Problem constants (match reference)
#define NB   32
#define NA   24564
#define NTOT (NB * NA)          // 786048 = 128 * 6141 exactly
#define NCH  85                 // 4 box deltas + 81 logits
#define TOPK 200
#define IOU_THR_F     0.5f
#define SCORE_FLOOR_F 0.01f

#define DEC_T 128               // decode block size (exact divisor of NTOT)
#define NMS_T 512               // nms block size
#define SLOTS ((NA + NMS_T - 1) / NMS_T)   // 48 anchors per thread
#define KPASS 8                 // winners selected per pass
#define NPOOL (2 * NMS_T)       // 1024 candidate entries (top-2 per thread)
// transposed key layout so each lane's 16 cached entries spread banks
#define CKADDR(e) ((((e) & 15) << 6) | ((e) >> 4))

// ---------------------------------------------------------------------------
// Kernel 1: decode boxes + softmax score/cls per anchor.
// LDS-staged coalesced input; per-thread arithmetic BIT-IDENTICAL to the
// R1-passing version (strict __f*_rn, exp in double). DO NOT alter numerics.
// ---------------------------------------------------------------------------
__global__ __launch_bounds__(DEC_T) void decode_kernel(
    const float* __restrict__ x, const float* __restrict__ anchor,
    float4* __restrict__ boxes, float* __restrict__ scores,
    float* __restrict__ clsf)
{
    __shared__ float tile[DEC_T * NCH];            // 43,520 B -> 3 blocks/CU

    const int base = blockIdx.x * DEC_T;
    const float4* src = (const float4*)(x + (size_t)base * NCH);
    float4* dst = (float4*)tile;
    for (int k = threadIdx.x; k < DEC_T * NCH / 4; k += DEC_T) dst[k] = src[k];
    __syncthreads();

    const int g = base + threadIdx.x;
    const int i = g % NA;
    const float* row = tile + threadIdx.x * NCH;

    float ax = anchor[i * 4 + 0];
    float ay = anchor[i * 4 + 1];
    float aw = anchor[i * 4 + 2];
    float ah = anchor[i * 4 + 3];

    float d0 = row[0], d1 = row[1], d2 = row[2], d3 = row[3];
    float cx = __fadd_rn(__fdiv_rn(__fmul_rn(d0, aw), 10.0f), ax);
    float cy = __fadd_rn(__fdiv_rn(__fmul_rn(d1, ah), 10.0f), ay);
    float w = __fmul_rn((float)exp((double)__fdiv_rn(d2, 5.0f)), aw);
    float h = __fmul_rn((float)exp((double)__fdiv_rn(d3, 5.0f)), ah);
    float hw = __fmul_rn(w, 0.5f);
    float hh = __fmul_rn(h, 0.5f);
    boxes[g] = make_float4(__fsub_rn(cx, hw), __fsub_rn(cy, hh),
                           __fadd_rn(cx, hw), __fadd_rn(cy, hh));

    const float* z = row + 4;
    float m = z[0];
    #pragma unroll 9
    for (int k = 1; k < 81; k++) m = fmaxf(m, z[k]);

    double S = 0.0;
    double be = 0.0;
    float  bz = -INFINITY;
    int    bj = 0;
    for (int k = 0; k < 81; k++) {
        float zk = z[k];
        double e = exp((double)__fsub_rn(zk, m));
        S += e;
        if (k >= 1 && zk > bz) { bz = zk; be = e; bj = k - 1; }
    }
    scores[g] = (float)(be / S);
    clsf[g]   = (float)bj;
}

// ---------------------------------------------------------------------------
// IoU suppression predicate — EXACT op sequence of the reference:
//   areas precomputed with the same __fmul_rn(__fsub_rn...) ops, clip extents
//   to [0,1], denom = (a1+a2)-common, correctly-rounded division, suppress on
//   !(iou < 0.5) (NaN suppresses). DO NOT replace the division with an
//   algebraic compare (1-ulp flips).
// v/a2 = candidate box/area, w/a1 = winner box/area (ref: box1 = winner).
// ---------------------------------------------------------------------------
__device__ __forceinline__ bool suppressed_by(const float4 v, const float a2,
                                              const float4 w, const float a1)
{
    float xl = fmaxf(w.x, v.x);
    float xr = fminf(w.z, v.z);
    float yt = fmaxf(w.y, v.y);
    float yb = fminf(w.w, v.w);
    float cw  = fminf(fmaxf(__fsub_rn(xr, xl), 0.0f), 1.0f);
    float chh = fminf(fmaxf(__fsub_rn(yb, yt), 0.0f), 1.0f);
    float common = __fmul_rn(cw, chh);
    float denom  = __fsub_rn(__fadd_rn(a1, a2), common);
    float iou    = __fdiv_rn(common, denom);
    return !(iou < IOU_THR_F);
}

// ---------------------------------------------------------------------------
// Kernel 2: per-batch greedy NMS, K=8 winners per pass (EAGER suppression).
//
// R1 lesson: lazy repair = serial dependent-latency chain, 5x WORSE. Eager
// 48-IoU scans are fine (parallel, ILP); the cost was per-winner overhead
// (2 barriers + reduce + atomic + dependent global winner load = ~20k cy of
// the 24k cy/winner). This version amortizes that overhead over 8 winners:
//
//  - Pass: each thread publishes top-2 candidates (key u64 + box) to an LDS
//    pool (1024 entries). Key = (score_bits<<32)|((NA-j)<<10)|e : order is
//    (score, NA-j) exactly as before — e bits sit BELOW the unique NA-j so
//    they never decide a comparison. Sentinel key = 1 for empty entries.
//  - ALL 8 waves redundantly run the identical serial selection (keys cached
//    in 16 u64 regs/lane): wave-max via shfl_xor butterfly -> verify vs this
//    pass's winners (<=7 IoUs, wave-uniform) -> select or consume. No
//    barriers/atomics/global loads inside; winners land in every thread's
//    registers (no broadcast step).
//  - hbound: hidden (3rd+) boxes of a thread are strictly below its 2nd-best
//    key. Consumes happen in strictly decreasing key order, so the SECOND
//    consume of a thread's pair is that bound. Pass ends when pool-max <=
//    hbound (checked BEFORE the score floor so hidden boxes aren't lost).
//    First selection of a pass always succeeds (hbound=0) -> progress.
//  - After the pass: explicit winner kills (self-IoU may be < thr — R2 bug),
//    then ONE fused loop: suppress vs the <=8 winners + top-2 rescan +
//    republish. 2 barriers per pass instead of 2 per winner.
//
// __launch_bounds__(512, 1) is LOAD-BEARING: without it the compiler caps
// at 128 VGPRs and spills the box array to scratch (R3: 11.2 GB FETCH).
// ---------------------------------------------------------------------------
__global__ __launch_bounds__(NMS_T, 1) void nms_kernel(
    const float4* __restrict__ boxes, const float* __restrict__ scores,
    const float* __restrict__ clsf, float* __restrict__ out)
{
    __shared__ float s_score[NA];                  // 98,256 B (own-slot reads only)
    __shared__ unsigned long long s_ckey[NPOOL];   //  8,192 B candidate keys
    __shared__ float4 s_cbox[NPOOL];               // 16,384 B candidate boxes

    const int b    = blockIdx.x;
    const int tid  = threadIdx.x;
    const int lane = tid & 63;
    const float*  sc = scores + (size_t)b * NA;
    const float4* bx = boxes  + (size_t)b * NA;
    const float*  cf = clsf   + (size_t)b * NA;
    float* ob = out + (size_t)b * TOPK * 6;

    float4 box[SLOTS];
    unsigned long long alive = 0ULL;
    #pragma unroll
    for (int s = 0; s < SLOTS; s++) {
        int j = tid + s * NMS_T;
        box[s] = make_float4(0.0f, 0.0f, 0.0f, 0.0f);
        if (j < NA) { box[s] = bx[j]; alive |= (1ULL << s); }
    }
    for (int j = tid; j < NA; j += NMS_T) s_score[j] = sc[j];
    // s_score entries are only ever read by the thread that wrote them.

    // pass-winner state — identical (uniform) across all waves every pass
    float4 wbox[KPASS]; float warea[KPASS]; float wscore[KPASS]; int wj[KPASS];
    int t = 0; bool gdone = false; int npass = 0;

    // ---- initial top-2 rescan + publish (no winners yet)
    {
        unsigned long long k1 = 0ULL, k2 = 0ULL; int j1 = -1, j2 = -1;
        #pragma unroll
        for (int s = 0; s < SLOTS; s++) {
            if (!(alive & (1ULL << s))) continue;
            int j = tid + s * NMS_T;
            unsigned long long kk =
                ((unsigned long long)__float_as_uint(s_score[j]) << 32) |
                ((unsigned long long)(unsigned)(NA - j) << 10);
            if (kk > k1)      { k2 = k1; j2 = j1; k1 = kk; j1 = j; }
            else if (kk > k2) { k2 = kk; j2 = j; }
        }
        int e0 = 2 * tid, e1 = 2 * tid + 1;
        s_ckey[CKADDR(e0)] = (j1 >= 0) ? (k1 | (unsigned long long)e0) : 1ULL;
        s_ckey[CKADDR(e1)] = (j2 >= 0) ? (k2 | (unsigned long long)e1) : 1ULL;
        if (j1 >= 0) s_cbox[e0] = bx[j1];
        if (j2 >= 0) s_cbox[e1] = bx[j2];
    }
    __syncthreads();

    while (true) {
        // ---- cache pool keys: lane L owns entries [L*16, L*16+16)
        unsigned long long ck[16];
        #pragma unroll
        for (int i = 0; i < 16; i++) ck[i] = s_ckey[(i << 6) | lane];

        // ---- selection loop (all waves redundantly; deterministic-identical)
        npass = 0;
        unsigned long long hbound = 0ULL;
        int kmax = TOPK - t; if (kmax > KPASS) kmax = KPASS;
        while (true) {
            unsigned long long lm = 0ULL;
            #pragma unroll
            for (int i = 0; i < 16; i++) if (ck[i] > lm) lm = ck[i];
            #pragma unroll
            for (int off = 32; off > 0; off >>= 1) {
                unsigned long long o = __shfl_xor(lm, off, 64);
                if (o > lm) lm = o;
            }
            // hbound check FIRST (a hidden 3rd-best may outrank the floor-fail)
            if (!(lm > hbound)) break;                    // end pass, rescan
            float ms = __uint_as_float((unsigned)(lm >> 32));
            if (!(ms >= SCORE_FLOOR_F)) { gdone = true; break; }

            int e  = (int)(lm & 1023ULL);
            int jw = NA - (int)((lm >> 10) & 0x7FFFULL);
            float4 cb = s_cbox[e];                        // uniform broadcast
            float  ca = __fmul_rn(__fsub_rn(cb.z, cb.x), __fsub_rn(cb.w, cb.y));

            bool kill = false;
            #pragma unroll
            for (int k = 0; k < KPASS; k++)
                if (k < npass)
                    kill |= suppressed_by(cb, ca, wbox[k], warea[k]);

            // consume entry e (owner lane zeroes key; second-of-pair => hbound)
            {
                int olane = e >> 4, oi = e & 15;
                unsigned long long pk = 0ULL;
                #pragma unroll
                for (int i = 0; i < 16; i++) if (i == (oi ^ 1)) pk = ck[i];
                // pk==0: partner consumed earlier (real); pk==1: empty sentinel
                unsigned long long hb_c =
                    (lane == olane && pk == 0ULL) ? lm : 0ULL;
                unsigned long long hb = __shfl(hb_c, olane, 64);
                if (hb > hbound) hbound = hb;
                #pragma unroll
                for (int i = 0; i < 16; i++)
                    if (lane == olane && i == oi) ck[i] = 0ULL;
            }

            if (!kill) {
                #pragma unroll
                for (int k = 0; k < KPASS; k++)
                    if (k == npass) {
                        wbox[k] = cb; warea[k] = ca; wscore[k] = ms; wj[k] = jw;
                    }
                npass++;
                if (npass == kmax) break;
            }
        }

        // ---- emit winners (owner thread writes row; cls via 1 global load)
        #pragma unroll
        for (int k = 0; k < KPASS; k++) {
            if (k < npass && tid == (wj[k] & (NMS_T - 1))) {
                float* o6 = ob + (size_t)(t + k) * 6;
                o6[0] = cf[wj[k]];
                o6[1] = wscore[k];
                o6[2] = wbox[k].x; o6[3] = wbox[k].y;
                o6[4] = wbox[k].z; o6[5] = wbox[k].w;
            }
        }
        t += npass;
        if (gdone || t >= TOPK) break;

        __syncthreads();   // B1: all pool reads done before republish

        // ---- explicit winner kills BEFORE rescan (self-IoU may be < thr,
        //      and a surviving winner must not be re-offered as a candidate)
        #pragma unroll
        for (int k = 0; k < KPASS; k++)
            if (k < npass && tid == (wj[k] & (NMS_T - 1)))
                alive &= ~(1ULL << (wj[k] >> 9));

        // ---- fused: suppress vs pass winners + top-2 rescan + republish
        {
            unsigned long long k1 = 0ULL, k2 = 0ULL; int j1 = -1, j2 = -1;
            #pragma unroll
            for (int s = 0; s < SLOTS; s++) {
                if (!(alive & (1ULL << s))) continue;
                float4 v = box[s];
                float a2 = __fmul_rn(__fsub_rn(v.z, v.x), __fsub_rn(v.w, v.y));
                bool dead = false;
                #pragma unroll
                for (int k = 0; k < KPASS; k++)
                    if (k < npass)
                        dead |= suppressed_by(v, a2, wbox[k], warea[k]);
                if (dead) { alive &= ~(1ULL << s); continue; }
                int j = tid + s * NMS_T;
                unsigned long long kk =
                    ((unsigned long long)__float_as_uint(s_score[j]) << 32) |
                    ((unsigned long long)(unsigned)(NA - j) << 10);
                if (kk > k1)      { k2 = k1; j2 = j1; k1 = kk; j1 = j; }
                else if (kk > k2) { k2 = kk; j2 = j; }
            }
            int e0 = 2 * tid, e1 = 2 * tid + 1;
            s_ckey[CKADDR(e0)] = (j1 >= 0) ? (k1 | (unsigned long long)e0) : 1ULL;
            s_ckey[CKADDR(e1)] = (j2 >= 0) ? (k2 | (unsigned long long)e1) : 1ULL;
            if (j1 >= 0) s_cbox[e0] = bx[j1];   // L2-resident reload
            if (j2 >= 0) s_cbox[e1] = bx[j2];
        }
        __syncthreads();   // B2: republish visible before next key-cache
    }

    for (int k = t * 6 + tid; k < TOPK * 6; k += NMS_T) ob[k] = 0.0f;
}

// ---------------------------------------------------------------------------
extern "C" void kernel_launch(void* const* d_in, const int* in_sizes, int n_in,
                              void* d_out, int out_size, void* d_ws, size_t ws_size,
                              hipStream_t stream) {
    const float* x      = (const float*)d_in[0];   // (32, 24564, 85)
    const float* anchor = (const float*)d_in[1];   // (24564, 4)
    float* out = (float*)d_out;                    // (32, 200, 6)

    char* ws = (char*)d_ws;
    const size_t boxes_bytes  = (size_t)NTOT * 16;
    const size_t scores_off   = (boxes_bytes + 255) & ~255ULL;
    const size_t scores_bytes = (size_t)NTOT * 4;
    const size_t cls_off      = (scores_off + scores_bytes + 255) & ~255ULL;

    float4* boxes  = (float4*)ws;
    float*  scores = (float*)(ws + scores_off);
    float*  clsf   = (float*)(ws + cls_off);

    decode_kernel<<<NTOT / DEC_T, DEC_T, 0, stream>>>(x, anchor, boxes, scores, clsf);
    nms_kernel<<<NB, NMS_T, 0, stream>>>(boxes, scores, clsf, out);
}